// Round 1
// baseline (231.120 us; speedup 1.0000x reference)
//
#include <hip/hip_runtime.h>

typedef unsigned long long u64;
typedef unsigned int u32;

static constexpr int N = 8192;
static constexpr int NW = N / 64;     // 128 u64 words per mask row
static constexpr int CAPE = 12288;    // max edge-list entries (obs ~7-8k)
static constexpr int RSEG = 32;       // rank j-segments (256 keys each)
static constexpr int RT = 256;        // sweep-kernel threads (4 waves: cheap barriers)
static constexpr int EPT = CAPE / RT; // edges per thread in sweep (48)
static constexpr int DCAP = 96;       // words covered by intra matrix (Nv<=6144; obs ~4096)

// ---------------- ws layout (bytes) ----------------
// [0, 131072)        float4 boxes_s[8192]
// [131072, 163840)   float  scores_s[8192]
// [163840, 196608)   float  areas_s[8192]
// [196608, 196612)   int    ecount
// [196672, 294976)   u64    edgeW[12288]   victim bitmasks
// [294976, 344128)   u32    edgeM[12288]   row | xb<<16
// [344128, 1392704)  u32    rank_partial[32*8192]
// ---------------------------------------------------

__device__ __forceinline__ u64 make_key(float s, int i) {
  // valid scores are >= 0.5 (positive): bit order == float order. +1 keeps
  // adj > 0 for valid; invalid -> 0 (sorts last). Low bits: stability (asc i).
  u32 adj = (s >= 0.5f) ? (__float_as_uint(s) + 1u) : 0u;
  return ((u64)adj << 32) | (u64)(u32)(N - 1 - i);
}

// Kernel 1: rank-by-counting. Block (ib, jb): stage keys of 256-key segment
// jb in LDS; thread owns i = ib*256+t; count keys > key_i.
// 32 segments -> 1024 blocks = 4 blocks/CU = 16 waves/CU (hides LDS latency;
// the old 8-segment version ran 1 block/CU and was latency-bound).
__global__ __launch_bounds__(256)
void rank_kernel(const float* __restrict__ conf, u32* __restrict__ rank_partial) {
  __shared__ u64 sk[256];
  const int t = threadIdx.x;
  const int jb = blockIdx.y;
  const int j = jb * 256 + t;
  sk[t] = make_key(conf[j], j);
  __syncthreads();
  const int i = blockIdx.x * 256 + t;
  const u64 ki = make_key(conf[i], i);
  int cnt = 0;
  #pragma unroll 8
  for (int k = 0; k < 256; ++k) cnt += (sk[k] > ki);
  rank_partial[jb * N + i] = (u32)cnt;
}

// Kernel 2: sum partial ranks, scatter into sorted arrays. Also zeroes ecount
// (runs before mask_kernel on the same stream; kernel-boundary ordering).
__global__ __launch_bounds__(256)
void scatter_kernel(const float4* __restrict__ xyxy, const float* __restrict__ conf,
                    const u32* __restrict__ rank_partial,
                    float4* __restrict__ boxes_s, float* __restrict__ scores_s,
                    float* __restrict__ areas_s, int* __restrict__ ecount) {
  #pragma clang fp contract(off)
  const int i = blockIdx.x * 256 + threadIdx.x;
  if (i == 0) *ecount = 0;
  u32 r = 0;
  #pragma unroll
  for (int jb = 0; jb < RSEG; ++jb) r += rank_partial[jb * N + i];
  float4 b = xyxy[i];
  boxes_s[r] = b;
  scores_s[r] = conf[i];
  areas_s[r] = (b.z - b.x) * (b.w - b.y);  // matches ref op order
}

// Kernel 3: IoU>0.5 edge emission. WG = 256 thr = 4 waves; wave w handles
// tile (xb = bx*4+w, yb = by). Skips lower triangle / invalid column words.
// Each wave with nonzero victims reserves slots via ONE global atomicAdd and
// writes compact edge records {victims u64, row|xb<<16}.
__global__ __launch_bounds__(256)
void mask_kernel(const float4* __restrict__ boxes_s, const float* __restrict__ areas_s,
                 const float* __restrict__ scores_s,
                 u64* __restrict__ edgeW, u32* __restrict__ edgeM,
                 int* __restrict__ ecount) {
  #pragma clang fp contract(off)
  __shared__ float4 cb[4][64];
  __shared__ float ca[4][64];
  const int wave = threadIdx.x >> 6;
  const int t = threadIdx.x & 63;
  const int xb = blockIdx.x * 4 + wave;  // column word index
  const int yb = blockIdx.y;             // row block index
  if (xb < yb) return;                   // wave-uniform exit
  if (scores_s[xb * 64] < 0.5f) return;  // whole column word invalid
  // per-wave staging; no barrier needed (same wave writes then reads)
  cb[wave][t] = boxes_s[xb * 64 + t];
  ca[wave][t] = areas_s[xb * 64 + t];
  const int i = yb * 64 + t;
  const float4 rb = boxes_s[i];
  const float ra = areas_s[i];
  const float sc_i = scores_s[i];
  const int jbase = xb * 64;
  u64 w = 0;
  for (int q = 0; q < 64; ++q) {
    float4 c = cb[wave][q];
    float ix1 = fmaxf(rb.x, c.x);
    float iy1 = fmaxf(rb.y, c.y);
    float ix2 = fminf(rb.z, c.z);
    float iy2 = fminf(rb.w, c.w);
    float iw = fmaxf(ix2 - ix1, 0.0f);
    float ih = fmaxf(iy2 - iy1, 0.0f);
    float inter = iw * ih;
    float uni = fmaxf((ra + ca[wave][q]) - inter, 1e-9f);
    float iou = inter / uni;  // IEEE f32 divide, matches numpy ref
    if ((iou > 0.5f) && (jbase + q > i)) w |= (1ull << q);
  }
  if (sc_i < 0.5f) w = 0;  // invalid owner row can never be kept: drop edges
  u64 nz = __ballot(w != 0ull);
  if (!nz) return;
  int base = 0;
  if (t == 0) base = atomicAdd(ecount, __popcll(nz));
  base = __shfl(base, 0);
  if (w) {
    int idx = base + __popcll(nz & ((1ull << t) - 1ull));  // rank in ballot
    if (idx < CAPE) {
      edgeW[idx] = w;
      edgeM[idx] = (u32)i | ((u32)xb << 16);
    }
  }
}

// Kernel 4: EXACT forward block-sweep + writeout (replaces the Jacobi fixpoint,
// whose iteration count = suppression-chain depth and dominated the runtime).
// Greedy NMS processed 64 sorted rows (one u64 word) at a time:
//   word y: removed[y] is final (suppression only flows to strictly greater
//   indices) -> thread 0 serially resolves intra-word suppression via the
//   D[y][q] victim matrix (only rows with intra edges, via intraM bitmask),
//   publishes keepm[y]; then all threads apply word-y rows' inter-word victim
//   masks. Deterministic ~64 word-steps x 2 cheap 4-wave barriers.
// Edges live in REGISTERS (coalesced burst load, 48/thread); the per-word scan
// is a 2-op v_bfe+v_cmp row-word match per slot, atomics only for live edges.
__global__ __launch_bounds__(256)
void sweep_write_kernel(const u64* __restrict__ edgeW, const u32* __restrict__ edgeM,
                        const int* __restrict__ ecount,
                        const float* __restrict__ scores_s,
                        const float4* __restrict__ boxes_s,
                        float* __restrict__ out) {
  __shared__ u64 validm[NW];
  __shared__ u64 keepm[NW];
  __shared__ u32 rem32[2 * NW];      // removed bitmask, as 2x u32 for atomics
  __shared__ u64 intraM[DCAP];       // rows with an intra-word edge
  __shared__ u64 D[DCAP][64];        // intra victim masks (only init'd where intraM set)
  __shared__ int NvS;
  const int tid = threadIdx.x;
  const int lane = tid & 63;

  // phase 0: zero small state (D needs no zeroing: read only where intraM set)
  if (tid == 0) NvS = 0;
  if (tid < NW) keepm[tid] = 0;
  rem32[tid] = 0;                    // 2*NW == 256 == blockDim
  if (tid < DCAP) intraM[tid] = 0;
  __syncthreads();

  // phase 1: valid masks + valid count (scores sorted desc -> valid is a prefix)
  for (int p = tid; p < N; p += RT) {
    u64 b = __ballot(scores_s[p] >= 0.5f);
    if (lane == 0) {
      validm[p >> 6] = b;
      atomicAdd(&NvS, __popcll(b));
    }
  }

  int E = *ecount;                   // broadcast scalar load
  if (E > CAPE) E = CAPE;

  // phase 2: burst-load edges into registers: thread owns e = tid + k*RT
  u64 ew[EPT]; u32 em[EPT];
  #pragma unroll
  for (int k = 0; k < EPT; ++k) {
    int e = tid + k * RT;
    if (e < E) { ew[k] = edgeW[e]; em[k] = edgeM[e]; }
    else       { ew[k] = 0; em[k] = 0xFFFFFFFFu; }   // inert: rw=1023 never matches
  }
  __syncthreads();                   // intraM zeros + validm + NvS visible

  // phase 3: divert intra edges (xb == row-word) into D + intraM
  #pragma unroll
  for (int k = 0; k < EPT; ++k) {
    u32 m_ = em[k];
    int row = (int)(m_ & 0xffffu);
    int x   = (int)(m_ >> 16);
    int rw  = row >> 6;
    if (x == rw && rw < DCAP) {
      D[rw][row & 63] = ew[k];
      atomicOr(&intraM[rw], 1ull << (row & 63));
      em[k] = 0xFFFFFFFFu;           // remove from inter set
    }
  }
  __syncthreads();

  int NWv = (NvS + 63) >> 6;         // valid rows are exactly [0, Nv)
  if (NWv > DCAP) NWv = DCAP;        // unreachable for this data (Nv ~ 4096)

  // phase 4: the sweep
  for (int y = 0; y < NWv; ++y) {
    __syncthreads();                 // word y-1's inter applies visible
    if (tid == 0) {
      u64 rm = ((u64)rem32[2 * y + 1] << 32) | (u64)rem32[2 * y];
      u64 kk = validm[y] & ~rm;
      u64 m = intraM[y] & kk;
      while (m) {                    // serial greedy within the word, asc q
        int q = __ffsll((long long)m) - 1;
        kk &= ~D[y][q];              // victims are strictly > q
        m &= ~(1ull << q);
        m &= kk;                     // rows q suppressed drop out
      }
      keepm[y] = kk;
    }
    __syncthreads();
    const u64 kpy = keepm[y];        // same-address LDS read: broadcast
    #pragma unroll
    for (int k = 0; k < EPT; ++k) {
      if (k * RT < E) {              // block-uniform: skip empty tail slots
        u32 m_ = em[k];
        if (((m_ >> 6) & 0x3FFu) == (u32)y) {       // row-word match (v_bfe+v_cmp)
          if ((kpy >> (m_ & 63u)) & 1ull) {         // owner row kept
            u32 x = m_ >> 16;                       // x > y strictly (intra diverted)
            atomicOr(&rem32[2 * x],     (u32)ew[k]);
            atomicOr(&rem32[2 * x + 1], (u32)(ew[k] >> 32));
          }
        }
      }
    }
  }
  __syncthreads();

  // Writeout: out[0..N*5) rows; out[N*5..N*6) keep flags as 0/1 f32.
  for (int s = tid; s < N; s += RT) {
    bool keep = (keepm[s >> 6] >> (s & 63)) & 1ull;
    float4 b = boxes_s[s];
    float sc = scores_s[s];
    float* row = out + (u64)s * 5;
    if (keep) {
      row[0] = b.x; row[1] = b.y; row[2] = b.z; row[3] = b.w; row[4] = sc;
      out[N * 5 + s] = 1.0f;
    } else {
      row[0] = 0.0f; row[1] = 0.0f; row[2] = 0.0f; row[3] = 0.0f; row[4] = 0.0f;
      out[N * 5 + s] = 0.0f;
    }
  }
}

extern "C" void kernel_launch(void* const* d_in, const int* in_sizes, int n_in,
                              void* d_out, int out_size, void* d_ws, size_t ws_size,
                              hipStream_t stream) {
  const float4* xyxy = (const float4*)d_in[0];
  const float* conf  = (const float*)d_in[1];
  char* ws = (char*)d_ws;
  float4* boxes_s   = (float4*)(ws + 0);
  float*  scores_s  = (float*)(ws + 131072);
  float*  areas_s   = (float*)(ws + 163840);
  int*    ecount    = (int*)(ws + 196608);
  u64*    edgeW     = (u64*)(ws + 196672);
  u32*    edgeM     = (u32*)(ws + 294976);
  u32*    rank_partial = (u32*)(ws + 344128);
  float*  out       = (float*)d_out;

  dim3 rg(N / 256, RSEG);
  rank_kernel<<<rg, 256, 0, stream>>>(conf, rank_partial);
  scatter_kernel<<<N / 256, 256, 0, stream>>>(xyxy, conf, rank_partial,
                                              boxes_s, scores_s, areas_s, ecount);
  dim3 mg(NW / 4, NW);
  mask_kernel<<<mg, 256, 0, stream>>>(boxes_s, areas_s, scores_s,
                                      edgeW, edgeM, ecount);
  sweep_write_kernel<<<1, 256, 0, stream>>>(edgeW, edgeM, ecount,
                                            scores_s, boxes_s, out);
}

// Round 2
// 171.591 us; speedup vs baseline: 1.3469x; 1.3469x over previous
//
#include <hip/hip_runtime.h>

typedef unsigned long long u64;
typedef unsigned int u32;

static constexpr int N = 8192;
static constexpr int NW = N / 64;   // 128 u64 words
static constexpr int RSEG = 32;     // rank j-segments (256 keys each)
static constexpr int CAPW = 512;    // per-word edge capacity (word-0 expected ~250, 512 = 16 sigma)

// ---------------- ws layout (bytes) ----------------
// [0, 131072)          float4 boxes_s[8192]
// [131072, 163840)     float  scores_s[8192]
// [163840, 196608)     float  areas_s[8192]
// [196608, 197120)     u32    cntG[128]      per-owner-word edge counts
// [197632, 1246208)    uint4  edge4[128*512] {mask.lo, mask.hi, row|xb<<16, 0}
// [1310720, 2359296)   u32    rank_partial[32*8192]
// ---------------------------------------------------

__device__ __forceinline__ u64 make_key(float s, int i) {
  // valid scores are >= 0.5 (positive): bit order == float order. +1 keeps
  // adj > 0 for valid; invalid -> 0 (sorts last). Low bits: stability (asc i).
  u32 adj = (s >= 0.5f) ? (__float_as_uint(s) + 1u) : 0u;
  return ((u64)adj << 32) | (u64)(u32)(N - 1 - i);
}

// Kernel 1: rank-by-counting. Block (ib, jb): stage 256-key segment jb in LDS;
// thread owns i = ib*256+t; count keys > key_i. 1024 blocks = 4 blocks/CU.
__global__ __launch_bounds__(256)
void rank_kernel(const float* __restrict__ conf, u32* __restrict__ rank_partial) {
  __shared__ u64 sk[256];
  const int t = threadIdx.x;
  const int jb = blockIdx.y;
  const int j = jb * 256 + t;
  sk[t] = make_key(conf[j], j);
  __syncthreads();
  const int i = blockIdx.x * 256 + t;
  const u64 ki = make_key(conf[i], i);
  int cnt = 0;
  #pragma unroll 8
  for (int k = 0; k < 256; ++k) cnt += (sk[k] > ki);
  rank_partial[jb * N + i] = (u32)cnt;
}

// Kernel 2: sum partial ranks, scatter into sorted arrays. Also zeroes cntG
// (runs before mask_kernel on the same stream; kernel-boundary ordering).
__global__ __launch_bounds__(256)
void scatter_kernel(const float4* __restrict__ xyxy, const float* __restrict__ conf,
                    const u32* __restrict__ rank_partial,
                    float4* __restrict__ boxes_s, float* __restrict__ scores_s,
                    float* __restrict__ areas_s, u32* __restrict__ cntG) {
  #pragma clang fp contract(off)
  const int i = blockIdx.x * 256 + threadIdx.x;
  if (blockIdx.x == 0 && threadIdx.x < NW) cntG[threadIdx.x] = 0;
  u32 r = 0;
  #pragma unroll
  for (int jb = 0; jb < RSEG; ++jb) r += rank_partial[jb * N + i];
  float4 b = xyxy[i];
  boxes_s[r] = b;
  scores_s[r] = conf[i];
  areas_s[r] = (b.z - b.x) * (b.w - b.y);  // matches ref op order
}

// Kernel 3: IoU>0.5 edge emission, CSR-by-construction: owner word yb owns
// segment edge4[yb*CAPW .. +CAPW). WG = 256 thr = 4 waves; wave w handles tile
// (xb = bx*4+w, yb). Skips lower triangle / invalid column words. One
// atomicAdd per wave on the per-word counter (low contention: <=64 waves/word).
__global__ __launch_bounds__(256)
void mask_kernel(const float4* __restrict__ boxes_s, const float* __restrict__ areas_s,
                 const float* __restrict__ scores_s,
                 uint4* __restrict__ edge4, u32* __restrict__ cntG) {
  #pragma clang fp contract(off)
  __shared__ float4 cb[4][64];
  __shared__ float ca[4][64];
  const int wave = threadIdx.x >> 6;
  const int t = threadIdx.x & 63;
  const int xb = blockIdx.x * 4 + wave;  // column word index
  const int yb = blockIdx.y;             // row (owner) word index
  if (xb < yb) return;                   // wave-uniform exit
  if (scores_s[xb * 64] < 0.5f) return;  // whole column word invalid
  // per-wave staging; no barrier needed (same wave writes then reads)
  cb[wave][t] = boxes_s[xb * 64 + t];
  ca[wave][t] = areas_s[xb * 64 + t];
  const int i = yb * 64 + t;
  const float4 rb = boxes_s[i];
  const float ra = areas_s[i];
  const float sc_i = scores_s[i];
  const int jbase = xb * 64;
  u64 w = 0;
  for (int q = 0; q < 64; ++q) {
    float4 c = cb[wave][q];
    float ix1 = fmaxf(rb.x, c.x);
    float iy1 = fmaxf(rb.y, c.y);
    float ix2 = fminf(rb.z, c.z);
    float iy2 = fminf(rb.w, c.w);
    float iw = fmaxf(ix2 - ix1, 0.0f);
    float ih = fmaxf(iy2 - iy1, 0.0f);
    float inter = iw * ih;
    float uni = fmaxf((ra + ca[wave][q]) - inter, 1e-9f);
    float iou = inter / uni;  // IEEE f32 divide, matches numpy ref
    if ((iou > 0.5f) && (jbase + q > i)) w |= (1ull << q);
  }
  if (sc_i < 0.5f) w = 0;  // invalid owner row can never be kept: drop edges
  u64 nz = __ballot(w != 0ull);
  if (!nz) return;
  int base = 0;
  if (t == 0) base = atomicAdd(&cntG[yb], (u32)__popcll(nz));
  base = __shfl(base, 0);
  if (w) {
    int idx = base + __popcll(nz & ((1ull << t) - 1ull));  // rank in ballot
    if (idx < CAPW) {
      edge4[(u64)yb * CAPW + idx] =
          make_uint4((u32)w, (u32)(w >> 32), (u32)i | ((u32)xb << 16), 0u);
    }
  }
}

// Kernel 4: EXACT forward sweep, ONE WAVE, ZERO barriers in the loop.
// Greedy keep is computed word-by-word in sorted order: word y's removed mask
// is final when reached (suppression flows strictly forward). Per word:
//  - next word's edge segment is prefetched into registers (hides HBM/L2 lat)
//  - rem[y] read from LDS; kk = valid & ~rem
//  - intra-word edges (xb==y, rare: ~1/word) resolved serially via D64 table
//  - lane-parallel: each lane applies its kept-owner edges via 2 LDS atomicOr
// Wave-synchronous => no s_barrier; LDS ops are in-order per wave (compiler
// inserts lgkmcnt). Critical chain ~400 cyc/word * ~64 words ~= 11 us.
__global__ __launch_bounds__(256)
void sweep_write_kernel(const uint4* __restrict__ edge4, const u32* __restrict__ cntG,
                        const float* __restrict__ scores_s,
                        const float4* __restrict__ boxes_s,
                        float* __restrict__ out) {
  __shared__ u64 validm[NW];
  __shared__ u64 keepm[NW];
  __shared__ u32 rem32[2 * NW];
  __shared__ u64 D64[64];
  __shared__ u32 intraLH[2];
  __shared__ u32 cntL[NW];
  __shared__ int NvS;
  const int tid = threadIdx.x;
  const int lane = tid & 63;

  if (tid == 0) NvS = 0;
  if (tid < NW) { keepm[tid] = 0; cntL[tid] = min(cntG[tid], (u32)CAPW); }
  rem32[tid] = 0;                        // 2*NW == 256 == blockDim
  for (int p = tid; p < N; p += 256) {
    u64 b = __ballot(scores_s[p] >= 0.5f);
    if (lane == 0) { validm[p >> 6] = b; atomicAdd(&NvS, __popcll(b)); }
  }
  __syncthreads();

  if (tid < 64) {                        // wave 0: the sweep
    const int t = tid;
    const int NWv = min((NvS + 63) >> 6, NW);  // valid rows are exactly [0, Nv)
    uint4 cur[8], nxt[8];
    #pragma unroll
    for (int ch = 0; ch < 8; ++ch) {
      cur[ch] = make_uint4(0u, 0u, 0u, 0u);
      nxt[ch] = make_uint4(0u, 0u, 0u, 0u);
    }
    int cnt = (NWv > 0) ? (int)cntL[0] : 0;
    #pragma unroll
    for (int ch = 0; ch < 8; ++ch)
      if (ch * 64 < cnt) cur[ch] = edge4[ch * 64 + t];

    for (int y = 0; y < NWv; ++y) {
      // prefetch word y+1 segment (read-only global; safe any time)
      int cntN = 0;
      if (y + 1 < NWv) {
        cntN = (int)cntL[y + 1];
        const uint4* pn = edge4 + (u64)(y + 1) * CAPW;
        #pragma unroll
        for (int ch = 0; ch < 8; ++ch)
          if (ch * 64 < cntN) nxt[ch] = pn[ch * 64 + t];
      }
      // intra collection (per-wave in-order LDS: zero precedes the atomicOrs)
      if (t == 0) { intraLH[0] = 0u; intraLH[1] = 0u; }
      #pragma unroll
      for (int ch = 0; ch < 8; ++ch) {
        if (ch * 64 + t < cnt) {
          u32 meta = cur[ch].z;
          if ((int)(meta >> 16) == y) {      // intra-word edge (unique q per record)
            int q = (int)(meta & 63u);
            D64[q] = ((u64)cur[ch].y << 32) | (u64)cur[ch].x;
            atomicOr(&intraLH[q >> 5], 1u << (q & 31));
          }
        }
      }
      // keep resolution: uniform across lanes (all LDS reads broadcast)
      u64 rm = ((u64)rem32[2 * y + 1] << 32) | (u64)rem32[2 * y];
      u64 kk = validm[y] & ~rm;
      u64 im = (((u64)intraLH[1] << 32) | (u64)intraLH[0]) & kk;
      while (im) {                            // serial greedy, asc q; D bits > q only
        int q = __ffsll((long long)im) - 1;
        kk &= ~D64[q];
        im &= ~(1ull << q);
        im &= kk;
      }
      if (t == 0) keepm[y] = kk;
      // apply inter edges of kept owners (x > y strictly)
      #pragma unroll
      for (int ch = 0; ch < 8; ++ch) {
        if (ch * 64 + t < cnt) {
          u32 meta = cur[ch].z;
          int x = (int)(meta >> 16);
          if (x != y && ((kk >> (meta & 63u)) & 1ull)) {
            atomicOr(&rem32[2 * x],     cur[ch].x);
            atomicOr(&rem32[2 * x + 1], cur[ch].y);
          }
        }
      }
      #pragma unroll
      for (int ch = 0; ch < 8; ++ch) cur[ch] = nxt[ch];
      cnt = cntN;
    }
  }
  __syncthreads();

  // Writeout: out[0..N*5) rows; out[N*5..N*6) keep flags as 0/1 f32.
  for (int s = tid; s < N; s += 256) {
    bool keep = (keepm[s >> 6] >> (s & 63)) & 1ull;
    float4 b = boxes_s[s];
    float sc = scores_s[s];
    float* row = out + (u64)s * 5;
    if (keep) {
      row[0] = b.x; row[1] = b.y; row[2] = b.z; row[3] = b.w; row[4] = sc;
      out[N * 5 + s] = 1.0f;
    } else {
      row[0] = 0.0f; row[1] = 0.0f; row[2] = 0.0f; row[3] = 0.0f; row[4] = 0.0f;
      out[N * 5 + s] = 0.0f;
    }
  }
}

extern "C" void kernel_launch(void* const* d_in, const int* in_sizes, int n_in,
                              void* d_out, int out_size, void* d_ws, size_t ws_size,
                              hipStream_t stream) {
  const float4* xyxy = (const float4*)d_in[0];
  const float* conf  = (const float*)d_in[1];
  char* ws = (char*)d_ws;
  float4* boxes_s   = (float4*)(ws + 0);
  float*  scores_s  = (float*)(ws + 131072);
  float*  areas_s   = (float*)(ws + 163840);
  u32*    cntG      = (u32*)(ws + 196608);
  uint4*  edge4     = (uint4*)(ws + 197632);
  u32*    rank_partial = (u32*)(ws + 1310720);
  float*  out       = (float*)d_out;

  dim3 rg(N / 256, RSEG);
  rank_kernel<<<rg, 256, 0, stream>>>(conf, rank_partial);
  scatter_kernel<<<N / 256, 256, 0, stream>>>(xyxy, conf, rank_partial,
                                              boxes_s, scores_s, areas_s, cntG);
  dim3 mg(NW / 4, NW);
  mask_kernel<<<mg, 256, 0, stream>>>(boxes_s, areas_s, scores_s, edge4, cntG);
  sweep_write_kernel<<<1, 256, 0, stream>>>(edge4, cntG, scores_s, boxes_s, out);
}

// Round 3
// 145.848 us; speedup vs baseline: 1.5847x; 1.1765x over previous
//
#include <hip/hip_runtime.h>

typedef unsigned long long u64;
typedef unsigned int u32;

static constexpr int N = 8192;
static constexpr int NW = N / 64;   // 128 u64 words
static constexpr int RSEG = 32;     // rank j-segments (256 keys each)
static constexpr int CAPW = 512;    // per-word edge capacity (word-0 expected ~250, 512 = 16 sigma)

// ---------------- ws layout (bytes) ----------------
// [0, 131072)          float4 boxes_s[8192]
// [131072, 163840)     float  scores_s[8192]
// [163840, 196608)     float  areas_s[8192]
// [196608, 197120)     u32    cntG[128]      per-owner-word edge counts
// [197632, 1246208)    uint4  edge4[128*512] {mask.lo, mask.hi, row|xb<<16, 0}
// [1310720, 2359296)   u32    rank_partial[32*8192]
// ---------------------------------------------------

__device__ __forceinline__ u64 make_key(float s, int i) {
  // valid scores are >= 0.5 (positive): bit order == float order. +1 keeps
  // adj > 0 for valid; invalid -> 0 (sorts last). Low bits: stability (asc i).
  u32 adj = (s >= 0.5f) ? (__float_as_uint(s) + 1u) : 0u;
  return ((u64)adj << 32) | (u64)(u32)(N - 1 - i);
}

// Kernel 1: rank-by-counting. Block (ib, jb): stage 256-key segment jb in LDS;
// thread owns i = ib*256+t; count keys > key_i. 1024 blocks = 4 blocks/CU.
__global__ __launch_bounds__(256)
void rank_kernel(const float* __restrict__ conf, u32* __restrict__ rank_partial) {
  __shared__ u64 sk[256];
  const int t = threadIdx.x;
  const int jb = blockIdx.y;
  const int j = jb * 256 + t;
  sk[t] = make_key(conf[j], j);
  __syncthreads();
  const int i = blockIdx.x * 256 + t;
  const u64 ki = make_key(conf[i], i);
  int cnt = 0;
  #pragma unroll 8
  for (int k = 0; k < 256; ++k) cnt += (sk[k] > ki);
  rank_partial[jb * N + i] = (u32)cnt;
}

// Kernel 2: sum partial ranks, scatter into sorted arrays. Also zeroes cntG
// (runs before mask_kernel on the same stream; kernel-boundary ordering).
__global__ __launch_bounds__(256)
void scatter_kernel(const float4* __restrict__ xyxy, const float* __restrict__ conf,
                    const u32* __restrict__ rank_partial,
                    float4* __restrict__ boxes_s, float* __restrict__ scores_s,
                    float* __restrict__ areas_s, u32* __restrict__ cntG) {
  #pragma clang fp contract(off)
  const int i = blockIdx.x * 256 + threadIdx.x;
  if (blockIdx.x == 0 && threadIdx.x < NW) cntG[threadIdx.x] = 0;
  u32 r = 0;
  #pragma unroll
  for (int jb = 0; jb < RSEG; ++jb) r += rank_partial[jb * N + i];
  float4 b = xyxy[i];
  boxes_s[r] = b;
  scores_s[r] = conf[i];
  areas_s[r] = (b.z - b.x) * (b.w - b.y);  // matches ref op order
}

// Kernel 3: IoU>0.5 edge emission, CSR-by-construction: owner word yb owns
// segment edge4[yb*CAPW .. +CAPW). WG = 256 thr = 4 waves; wave w handles tile
// (xb = bx*4+w, yb). Skips lower triangle / invalid column words. One
// atomicAdd per wave on the per-word counter (low contention: <=64 waves/word).
__global__ __launch_bounds__(256)
void mask_kernel(const float4* __restrict__ boxes_s, const float* __restrict__ areas_s,
                 const float* __restrict__ scores_s,
                 uint4* __restrict__ edge4, u32* __restrict__ cntG) {
  #pragma clang fp contract(off)
  __shared__ float4 cb[4][64];
  __shared__ float ca[4][64];
  const int wave = threadIdx.x >> 6;
  const int t = threadIdx.x & 63;
  const int xb = blockIdx.x * 4 + wave;  // column word index
  const int yb = blockIdx.y;             // row (owner) word index
  if (xb < yb) return;                   // wave-uniform exit
  if (scores_s[xb * 64] < 0.5f) return;  // whole column word invalid
  // per-wave staging; no barrier needed (same wave writes then reads)
  cb[wave][t] = boxes_s[xb * 64 + t];
  ca[wave][t] = areas_s[xb * 64 + t];
  const int i = yb * 64 + t;
  const float4 rb = boxes_s[i];
  const float ra = areas_s[i];
  const float sc_i = scores_s[i];
  const int jbase = xb * 64;
  u64 w = 0;
  for (int q = 0; q < 64; ++q) {
    float4 c = cb[wave][q];
    float ix1 = fmaxf(rb.x, c.x);
    float iy1 = fmaxf(rb.y, c.y);
    float ix2 = fminf(rb.z, c.z);
    float iy2 = fminf(rb.w, c.w);
    float iw = fmaxf(ix2 - ix1, 0.0f);
    float ih = fmaxf(iy2 - iy1, 0.0f);
    float inter = iw * ih;
    float uni = fmaxf((ra + ca[wave][q]) - inter, 1e-9f);
    float iou = inter / uni;  // IEEE f32 divide, matches numpy ref
    if ((iou > 0.5f) && (jbase + q > i)) w |= (1ull << q);
  }
  if (sc_i < 0.5f) w = 0;  // invalid owner row can never be kept: drop edges
  u64 nz = __ballot(w != 0ull);
  if (!nz) return;
  int base = 0;
  if (t == 0) base = atomicAdd(&cntG[yb], (u32)__popcll(nz));
  base = __shfl(base, 0);
  if (w) {
    int idx = base + __popcll(nz & ((1ull << t) - 1ull));  // rank in ballot
    if (idx < CAPW) {
      edge4[(u64)yb * CAPW + idx] =
          make_uint4((u32)w, (u32)(w >> 32), (u32)i | ((u32)xb << 16), 0u);
    }
  }
}

// Kernel 4: EXACT forward sweep, ONE WAVE, ZERO barriers in the loop.
// Same algorithm as round 2 (proven correct) with the spill/latency fixes:
//  - __launch_bounds__(256,1): lift the 48-VGPR cap that spilled cur[]/nxt[]
//    (16 uint4 = 64 VGPR of edge buffers) to scratch -> ~1.3K cyc/step of
//    scratch traffic on the serial chain.
//  - intra-table D64: zero via lane-parallel D64[t]=0, presence via lane-t
//    readback + __ballot (replaces zero->atomicOr->read chain); greedy loop
//    reads D64[q] via __shfl from the owning lane (VALU) instead of LDS.
//  - unconditional, clamped prefetch + channel loads (validity checked at use
//    only): no select-keep-old chains, stable codegen.
__global__ __launch_bounds__(256, 1)
void sweep_write_kernel(const uint4* __restrict__ edge4, const u32* __restrict__ cntG,
                        const float* __restrict__ scores_s,
                        const float4* __restrict__ boxes_s,
                        float* __restrict__ out) {
  __shared__ u64 validm[NW];
  __shared__ u64 keepm[NW];
  __shared__ u32 rem32[2 * NW];
  __shared__ u64 D64[64];
  __shared__ u32 cntL[NW];
  __shared__ int NvS;
  const int tid = threadIdx.x;
  const int lane = tid & 63;

  if (tid == 0) NvS = 0;
  if (tid < NW) { keepm[tid] = 0; cntL[tid] = min(cntG[tid], (u32)CAPW); }
  rem32[tid] = 0;                        // 2*NW == 256 == blockDim
  for (int p = tid; p < N; p += 256) {
    u64 b = __ballot(scores_s[p] >= 0.5f);
    if (lane == 0) { validm[p >> 6] = b; atomicAdd(&NvS, __popcll(b)); }
  }
  __syncthreads();

  if (tid < 64) {                        // wave 0: the sweep
    const int t = tid;
    const int NWv = min((NvS + 63) >> 6, NW);  // valid rows are exactly [0, Nv)
    if (NWv > 0) {
      uint4 cur[8], nxt[8];
      #pragma unroll
      for (int ch = 0; ch < 8; ++ch) cur[ch] = edge4[ch * 64 + t];
      int cnt = (int)cntL[0];

      for (int y = 0; y < NWv; ++y) {
        // early LDS reads (in-order DS pipe: sees all prior steps' applies)
        u32 r0 = rem32[2 * y];
        u32 r1 = rem32[2 * y + 1];
        u64 vv = validm[y];
        // intra victim table: zero own slot, scatter records, read back
        D64[t] = 0;
        #pragma unroll
        for (int ch = 0; ch < 8; ++ch) {
          if (ch * 64 + t < cnt) {
            u32 meta = cur[ch].z;
            if ((int)(meta >> 16) == y)   // unique q per intra record
              D64[meta & 63u] = ((u64)cur[ch].y << 32) | (u64)cur[ch].x;
          }
        }
        u64 myD = D64[t];
        // prefetch next word's segment (unconditional, clamped: always safe)
        int seg = (y + 1 < NW) ? (y + 1) : (NW - 1);
        int cntN = (int)cntL[seg];
        const uint4* pn = edge4 + (u64)seg * CAPW;
        #pragma unroll
        for (int ch = 0; ch < 8; ++ch) nxt[ch] = pn[ch * 64 + t];
        // keep resolution (uniform across lanes)
        u64 kk = vv & ~(((u64)r1 << 32) | (u64)r0);
        u64 im = __ballot(myD != 0ull) & kk;
        while (im) {                      // serial greedy, asc q; D bits > q only
          int q = __ffsll((long long)im) - 1;
          u32 dlo = __shfl((u32)myD, q);
          u32 dhi = __shfl((u32)(myD >> 32), q);
          kk &= ~(((u64)dhi << 32) | (u64)dlo);
          im &= ~(1ull << q);
          im &= kk;
        }
        if (t == 0) keepm[y] = kk;
        // apply edges of kept owners (intra self-apply to rem[y] is harmless:
        // rem[y] already consumed; suppressed owners fail the kk test)
        #pragma unroll
        for (int ch = 0; ch < 8; ++ch) {
          if (ch * 64 + t < cnt) {
            u32 meta = cur[ch].z;
            if ((kk >> (meta & 63u)) & 1ull) {
              int x = (int)(meta >> 16);
              atomicOr(&rem32[2 * x],     cur[ch].x);
              atomicOr(&rem32[2 * x + 1], cur[ch].y);
            }
          }
        }
        #pragma unroll
        for (int ch = 0; ch < 8; ++ch) cur[ch] = nxt[ch];
        cnt = cntN;
      }
    }
  }
  __syncthreads();

  // Writeout: out[0..N*5) rows; out[N*5..N*6) keep flags as 0/1 f32.
  for (int s = tid; s < N; s += 256) {
    bool keep = (keepm[s >> 6] >> (s & 63)) & 1ull;
    float4 b = boxes_s[s];
    float sc = scores_s[s];
    float* row = out + (u64)s * 5;
    if (keep) {
      row[0] = b.x; row[1] = b.y; row[2] = b.z; row[3] = b.w; row[4] = sc;
      out[N * 5 + s] = 1.0f;
    } else {
      row[0] = 0.0f; row[1] = 0.0f; row[2] = 0.0f; row[3] = 0.0f; row[4] = 0.0f;
      out[N * 5 + s] = 0.0f;
    }
  }
}

extern "C" void kernel_launch(void* const* d_in, const int* in_sizes, int n_in,
                              void* d_out, int out_size, void* d_ws, size_t ws_size,
                              hipStream_t stream) {
  const float4* xyxy = (const float4*)d_in[0];
  const float* conf  = (const float*)d_in[1];
  char* ws = (char*)d_ws;
  float4* boxes_s   = (float4*)(ws + 0);
  float*  scores_s  = (float*)(ws + 131072);
  float*  areas_s   = (float*)(ws + 163840);
  u32*    cntG      = (u32*)(ws + 196608);
  uint4*  edge4     = (uint4*)(ws + 197632);
  u32*    rank_partial = (u32*)(ws + 1310720);
  float*  out       = (float*)d_out;

  dim3 rg(N / 256, RSEG);
  rank_kernel<<<rg, 256, 0, stream>>>(conf, rank_partial);
  scatter_kernel<<<N / 256, 256, 0, stream>>>(xyxy, conf, rank_partial,
                                              boxes_s, scores_s, areas_s, cntG);
  dim3 mg(NW / 4, NW);
  mask_kernel<<<mg, 256, 0, stream>>>(boxes_s, areas_s, scores_s, edge4, cntG);
  sweep_write_kernel<<<1, 256, 0, stream>>>(edge4, cntG, scores_s, boxes_s, out);
}

// Round 4
// 140.151 us; speedup vs baseline: 1.6491x; 1.0406x over previous
//
#include <hip/hip_runtime.h>

typedef unsigned long long u64;
typedef unsigned int u32;

static constexpr int N = 8192;
static constexpr int NW = N / 64;    // 128 u64 words
static constexpr int RSEG = 32;      // rank j-segments (256 keys each)
static constexpr int CAPW = 512;     // per-word edge capacity in global CSR
static constexpr int ECAP = 10240;   // LDS edge capacity, records (obs total ~7-8k)

// ---------------- ws layout (bytes) ----------------
// [0, 131072)         float4 boxes_s[8192]
// [131072, 163840)    float  scores_s[8192]
// [163840, 196608)    float  areas_s[8192]
// [196608, 197120)    u32    cntG[128]        per-owner-word INTER edge counts
// [197120, 197124)    int    nvG              valid-box count
// [197184, 198208)    u64    validmG[128]     valid bitmask (sorted order)
// [198208, 199232)    u64    keepmG[128]      sweep result
// [199680, 265216)    u64    Dg[128*64]       intra-word victim masks (dense)
// [265216, 1313792)   uint4  edge4[128*512]   inter edges {m.lo, m.hi, row|x<<16, 0}
// [1313792, 2362368)  u32    rank_partial[32*8192]
// ---------------------------------------------------

__device__ __forceinline__ u64 make_key(float s, int i) {
  // valid scores are >= 0.5 (positive): bit order == float order. +1 keeps
  // adj > 0 for valid; invalid -> 0 (sorts last). Low bits: stability (asc i).
  u32 adj = (s >= 0.5f) ? (__float_as_uint(s) + 1u) : 0u;
  return ((u64)adj << 32) | (u64)(u32)(N - 1 - i);
}

// Kernel 1: rank-by-counting. Block (ib, jb): stage 256-key segment jb in LDS;
// thread owns i = ib*256+t; count keys > key_i. 1024 blocks = 4 blocks/CU.
// Block (0,0) also zeroes the small cross-kernel state (kernel-boundary order).
__global__ __launch_bounds__(256)
void rank_kernel(const float* __restrict__ conf, u32* __restrict__ rank_partial,
                 u32* __restrict__ cntG, u64* __restrict__ validmG,
                 int* __restrict__ nvG) {
  __shared__ u64 sk[256];
  const int t = threadIdx.x;
  if (blockIdx.x == 0 && blockIdx.y == 0) {
    if (t < NW) { cntG[t] = 0; validmG[t] = 0; }
    if (t == 0) *nvG = 0;
  }
  const int jb = blockIdx.y;
  const int j = jb * 256 + t;
  sk[t] = make_key(conf[j], j);
  __syncthreads();
  const int i = blockIdx.x * 256 + t;
  const u64 ki = make_key(conf[i], i);
  int cnt = 0;
  #pragma unroll 8
  for (int k = 0; k < 256; ++k) cnt += (sk[k] > ki);
  rank_partial[jb * N + i] = (u32)cnt;
}

// Kernel 2: sum partial ranks, scatter into sorted arrays; also set the valid
// bit at the sorted position and count valid boxes.
__global__ __launch_bounds__(256)
void scatter_kernel(const float4* __restrict__ xyxy, const float* __restrict__ conf,
                    const u32* __restrict__ rank_partial,
                    float4* __restrict__ boxes_s, float* __restrict__ scores_s,
                    float* __restrict__ areas_s, u64* __restrict__ validmG,
                    int* __restrict__ nvG) {
  #pragma clang fp contract(off)
  const int i = blockIdx.x * 256 + threadIdx.x;
  u32 r = 0;
  #pragma unroll
  for (int jb = 0; jb < RSEG; ++jb) r += rank_partial[jb * N + i];
  float4 b = xyxy[i];
  float c = conf[i];
  boxes_s[r] = b;
  scores_s[r] = c;
  areas_s[r] = (b.z - b.x) * (b.w - b.y);  // matches ref op order
  if (c >= 0.5f) {
    atomicOr(&validmG[r >> 6], 1ull << (r & 63));
    atomicAdd(nvG, 1);                     // wave-coalesced by compiler
  }
}

// Kernel 3: IoU>0.5 edge emission. Diagonal tiles (xb==yb) write the dense
// intra-word victim array Dg[yb][t] (row t's victims within its own word,
// strictly-forward bits by construction). Off-diagonal tiles emit CSR inter
// edges into the owner word's segment edge4[yb*CAPW..).
__global__ __launch_bounds__(256)
void mask_kernel(const float4* __restrict__ boxes_s, const float* __restrict__ areas_s,
                 const float* __restrict__ scores_s,
                 uint4* __restrict__ edge4, u32* __restrict__ cntG,
                 u64* __restrict__ Dg) {
  #pragma clang fp contract(off)
  __shared__ float4 cb[4][64];
  __shared__ float ca[4][64];
  const int wave = threadIdx.x >> 6;
  const int t = threadIdx.x & 63;
  const int xb = blockIdx.x * 4 + wave;  // column word index
  const int yb = blockIdx.y;             // row (owner) word index
  if (xb < yb) return;                   // wave-uniform exit
  if (scores_s[xb * 64] < 0.5f) return;  // whole column word invalid
  // per-wave staging; no barrier needed (same wave writes then reads)
  cb[wave][t] = boxes_s[xb * 64 + t];
  ca[wave][t] = areas_s[xb * 64 + t];
  const int i = yb * 64 + t;
  const float4 rb = boxes_s[i];
  const float ra = areas_s[i];
  const float sc_i = scores_s[i];
  const int jbase = xb * 64;
  u64 w = 0;
  for (int q = 0; q < 64; ++q) {
    float4 c = cb[wave][q];
    float ix1 = fmaxf(rb.x, c.x);
    float iy1 = fmaxf(rb.y, c.y);
    float ix2 = fminf(rb.z, c.z);
    float iy2 = fminf(rb.w, c.w);
    float iw = fmaxf(ix2 - ix1, 0.0f);
    float ih = fmaxf(iy2 - iy1, 0.0f);
    float inter = iw * ih;
    float uni = fmaxf((ra + ca[wave][q]) - inter, 1e-9f);
    float iou = inter / uni;  // IEEE f32 divide, matches numpy ref
    if ((iou > 0.5f) && (jbase + q > i)) w |= (1ull << q);
  }
  if (sc_i < 0.5f) w = 0;  // invalid owner row can never be kept: drop edges
  if (xb == yb) {          // intra-word: dense write, all 64 lanes
    Dg[(u64)yb * 64 + t] = w;
    return;
  }
  u64 nz = __ballot(w != 0ull);
  if (!nz) return;
  int base = 0;
  if (t == 0) base = atomicAdd(&cntG[yb], (u32)__popcll(nz));
  base = __shfl(base, 0);
  if (w) {
    int idx = base + __popcll(nz & ((1ull << t) - 1ull));  // rank in ballot
    if (idx < CAPW) {
      edge4[(u64)yb * CAPW + idx] =
          make_uint4((u32)w, (u32)(w >> 32), (u32)i | ((u32)xb << 16), 0u);
    }
  }
}

// Kernel 4: EXACT forward sweep, one wave, zero barriers in the loop.
// Edges live in LDS (CSR, staged once by all 4 waves); intra masks arrive via
// distance-2 prefetched global loads of Dg; offsets/valid-masks are served
// from lane registers by shfl. The only chained LDS op per word is the
// rem32 read. keepm is exported to global; writeout is a separate kernel.
__global__ __launch_bounds__(256, 1)
void sweep_kernel(const uint4* __restrict__ edge4, const u32* __restrict__ cntG,
                  const u64* __restrict__ validmG, const int* __restrict__ nvG,
                  const u64* __restrict__ Dg, u64* __restrict__ keepmG) {
  __shared__ u64 maskL[ECAP];
  __shared__ u32 metaL[ECAP];
  __shared__ u32 offL[NW + 1];
  __shared__ u64 keepL[NW];
  __shared__ u32 rem32[2 * NW];
  __shared__ u32 cntL[NW];
  const int tid = threadIdx.x;
  const int wv = tid >> 6;
  const int t = tid & 63;

  if (tid < NW) { cntL[tid] = min(cntG[tid], (u32)CAPW); keepL[tid] = 0; }
  rem32[tid] = 0;                      // 2*NW == 256 == blockDim
  __syncthreads();

  if (tid < 64) {                      // wave 0: prefix scan -> offL (clamped)
    u32 a = cntL[t];
    u32 b = cntL[64 + t];
    #pragma unroll
    for (int d = 1; d < 64; d <<= 1) { u32 n = __shfl_up(a, d); if (t >= d) a += n; }
    u32 tot = __shfl(a, 63);
    #pragma unroll
    for (int d = 1; d < 64; d <<= 1) { u32 n = __shfl_up(b, d); if (t >= d) b += n; }
    b += tot;
    a = min(a, (u32)ECAP);
    b = min(b, (u32)ECAP);
    if (t == 0) offL[0] = 0;
    offL[1 + t] = a;
    offL[65 + t] = b;
  }
  __syncthreads();

  // stage inter edges into LDS CSR (wave wv handles words wv, wv+4, ...)
  for (int w = wv; w < NW; w += 4) {
    u32 o = offL[w];
    u32 ce = offL[w + 1] - o;
    const uint4* src = edge4 + (u64)w * CAPW;
    for (u32 s = t; s < ce; s += 64) {
      uint4 r = src[s];
      maskL[o + s] = ((u64)r.y << 32) | (u64)r.x;
      metaL[o + s] = r.z;
    }
  }
  __syncthreads();

  if (tid < 64) {                      // wave 0: the serial sweep
    const int NWv = min((*nvG + 63) >> 6, NW);  // valid rows are exactly [0, Nv)
    if (NWv > 0) {
      // lane-register tables, served by shfl (no LDS on the chain)
      u64 vr0 = validmG[t];
      u64 vr1 = validmG[64 + t];
      u32 or0 = offL[t];
      u32 or1 = offL[64 + t];
      u32 or2 = offL[128];
      // intra prefetch, distance 2
      u64 dc = Dg[t];
      u64 dn = Dg[(u64)((NWv > 1) ? 1 : 0) * 64 + t];

      for (int y = 0; y < NWv; ++y) {
        int yp = (y + 2 < NWv) ? (y + 2) : (NWv - 1);
        u64 dnn = Dg[(u64)yp * 64 + t];
        // offsets via shfl
        u32 o  = (y < 64) ? __shfl(or0, y) : __shfl(or1, y - 64);
        u32 oe = (y + 1 < 64) ? __shfl(or0, y + 1)
               : (y + 1 < 128) ? __shfl(or1, y + 1 - 64) : or2;
        u32 ce = oe - o;
        // edge preload (<=4 rounds; fallback loop beyond 256 records)
        u32 meta0 = 0, meta1 = 0, meta2 = 0, meta3 = 0;
        u64 m0 = 0, m1 = 0, m2 = 0, m3 = 0;
        if (t < ce)       { meta0 = metaL[o + t];       m0 = maskL[o + t]; }
        if (64 + t < ce)  { meta1 = metaL[o + 64 + t];  m1 = maskL[o + 64 + t]; }
        if (128 + t < ce) { meta2 = metaL[o + 128 + t]; m2 = maskL[o + 128 + t]; }
        if (192 + t < ce) { meta3 = metaL[o + 192 + t]; m3 = maskL[o + 192 + t]; }
        // rem / valid / keep resolution (uniform across lanes)
        u32 r0 = rem32[2 * y];
        u32 r1 = rem32[2 * y + 1];
        u64 vv = (y < 64) ? __shfl(vr0, y) : __shfl(vr1, y - 64);
        u64 kk = vv & ~(((u64)r1 << 32) | (u64)r0);
        u64 im = __ballot(dc != 0ull) & kk;
        while (im) {                   // serial greedy, asc q; D bits > q only
          int q = __ffsll((long long)im) - 1;
          u64 dq = __shfl(dc, q);
          kk &= ~dq;
          im &= ~(1ull << q);
          im &= kk;
        }
        if (t == 0) keepL[y] = kk;
        // apply inter edges of kept owners (x > y strictly)
        if (t < ce && ((kk >> (meta0 & 63u)) & 1ull)) {
          u32 x = meta0 >> 16;
          atomicOr(&rem32[2 * x], (u32)m0);
          atomicOr(&rem32[2 * x + 1], (u32)(m0 >> 32));
        }
        if (64 + t < ce && ((kk >> (meta1 & 63u)) & 1ull)) {
          u32 x = meta1 >> 16;
          atomicOr(&rem32[2 * x], (u32)m1);
          atomicOr(&rem32[2 * x + 1], (u32)(m1 >> 32));
        }
        if (128 + t < ce && ((kk >> (meta2 & 63u)) & 1ull)) {
          u32 x = meta2 >> 16;
          atomicOr(&rem32[2 * x], (u32)m2);
          atomicOr(&rem32[2 * x + 1], (u32)(m2 >> 32));
        }
        if (192 + t < ce && ((kk >> (meta3 & 63u)) & 1ull)) {
          u32 x = meta3 >> 16;
          atomicOr(&rem32[2 * x], (u32)m3);
          atomicOr(&rem32[2 * x + 1], (u32)(m3 >> 32));
        }
        for (u32 s = 256 + t; s < ce; s += 64) {  // rare overflow rounds
          u32 meta = metaL[o + s];
          u64 m = maskL[o + s];
          if ((kk >> (meta & 63u)) & 1ull) {
            u32 x = meta >> 16;
            atomicOr(&rem32[2 * x], (u32)m);
            atomicOr(&rem32[2 * x + 1], (u32)(m >> 32));
          }
        }
        dc = dn;
        dn = dnn;
      }
    }
  }
  __syncthreads();
  if (tid < NW) keepmG[tid] = keepL[tid];
}

// Kernel 5: parallel writeout (off the 1-CU critical path).
// out[0..N*5) rows; out[N*5..N*6) keep flags as 0/1 f32.
__global__ __launch_bounds__(256)
void writeout_kernel(const u64* __restrict__ keepmG,
                     const float4* __restrict__ boxes_s,
                     const float* __restrict__ scores_s,
                     float* __restrict__ out) {
  const int s = blockIdx.x * 256 + threadIdx.x;
  bool keep = (keepmG[s >> 6] >> (s & 63)) & 1ull;
  float4 b = boxes_s[s];
  float sc = scores_s[s];
  float* row = out + (u64)s * 5;
  if (keep) {
    row[0] = b.x; row[1] = b.y; row[2] = b.z; row[3] = b.w; row[4] = sc;
    out[N * 5 + s] = 1.0f;
  } else {
    row[0] = 0.0f; row[1] = 0.0f; row[2] = 0.0f; row[3] = 0.0f; row[4] = 0.0f;
    out[N * 5 + s] = 0.0f;
  }
}

extern "C" void kernel_launch(void* const* d_in, const int* in_sizes, int n_in,
                              void* d_out, int out_size, void* d_ws, size_t ws_size,
                              hipStream_t stream) {
  const float4* xyxy = (const float4*)d_in[0];
  const float* conf  = (const float*)d_in[1];
  char* ws = (char*)d_ws;
  float4* boxes_s   = (float4*)(ws + 0);
  float*  scores_s  = (float*)(ws + 131072);
  float*  areas_s   = (float*)(ws + 163840);
  u32*    cntG      = (u32*)(ws + 196608);
  int*    nvG       = (int*)(ws + 197120);
  u64*    validmG   = (u64*)(ws + 197184);
  u64*    keepmG    = (u64*)(ws + 198208);
  u64*    Dg        = (u64*)(ws + 199680);
  uint4*  edge4     = (uint4*)(ws + 265216);
  u32*    rank_partial = (u32*)(ws + 1313792);
  float*  out       = (float*)d_out;

  dim3 rg(N / 256, RSEG);
  rank_kernel<<<rg, 256, 0, stream>>>(conf, rank_partial, cntG, validmG, nvG);
  scatter_kernel<<<N / 256, 256, 0, stream>>>(xyxy, conf, rank_partial,
                                              boxes_s, scores_s, areas_s,
                                              validmG, nvG);
  dim3 mg(NW / 4, NW);
  mask_kernel<<<mg, 256, 0, stream>>>(boxes_s, areas_s, scores_s,
                                      edge4, cntG, Dg);
  sweep_kernel<<<1, 256, 0, stream>>>(edge4, cntG, validmG, nvG, Dg, keepmG);
  writeout_kernel<<<N / 256, 256, 0, stream>>>(keepmG, boxes_s, scores_s, out);
}